// Round 11
// baseline (311.042 us; speedup 1.0000x reference)
//
#include <hip/hip_runtime.h>
#include <hip/hip_bf16.h>
#include <math.h>

#define VOLF 100.0f
#define FD 32
#define OUT_DIM 10
#define MAXN 320
#define MAX_LAUNCH_ITERS 4
#define OB 128     // k_out partial blocks
#define CHUNK 28   // k_act0: k's per LDS chunk
#define NCHUNK 7   // 196/28 chunks per block
#define LDP 68     // padded wtT row stride
#define PS 8       // partial slots
#define NCD 5      // bin cells per dim (x,y)
#define CELLW 20.0f
#define NCELL (NCD*NCD)

// ---------------- K1: merged tiled x-transpose + per-neuron preprocess ----------------
__global__ __launch_bounds__(256) void k_prext(
    const float* __restrict__ x, const float* __restrict__ positions,
    const float* __restrict__ radii_in, const float* __restrict__ features,
    float* __restrict__ xT, float* __restrict__ posx4,
    float* __restrict__ radii, float* __restrict__ e_iw, float* __restrict__ e_ow,
    float* __restrict__ fn, float* __restrict__ scal, int N, int IN, int nxt)
{
    __shared__ float tile[64][65];
    __shared__ float red[256];
    if ((int)blockIdx.x < nxt) {           // tiled transpose: 64 k x 64 b per block
        int w = threadIdx.x >> 6, lane = threadIdx.x & 63;
        int k0 = blockIdx.x * 64;
        #pragma unroll
        for (int r = 0; r < 16; r++) {
            int b = w * 16 + r;
            int k = k0 + lane;
            if (k < IN) tile[lane][b] = x[(size_t)b * IN + k];
        }
        __syncthreads();
        #pragma unroll
        for (int r = 0; r < 16; r++) {
            int kl = w * 16 + r;
            int k = k0 + kl;
            if (k < IN) xT[(size_t)k * 64 + lane] = tile[kl][lane];
        }
        return;
    }
    int i = (blockIdx.x - nxt) * 256 + threadIdx.x;
    float my_iw = 0.0f, my_ow = 0.0f, my_r = 0.0f;
    if (i < N) {
        float px = fminf(fmaxf(positions[3*i+0], 0.1f), VOLF - 0.1f);
        float py = fminf(fmaxf(positions[3*i+1], 0.1f), VOLF - 0.1f);
        float pz = fminf(fmaxf(positions[3*i+2], 0.1f), VOLF - 0.1f);
        float sq = px*px + py*py + pz*pz;
        posx4[4*i+0] = px; posx4[4*i+1] = py; posx4[4*i+2] = pz; posx4[4*i+3] = sq;
        float r = fminf(fmaxf(radii_in[i], 1.0f), 50.0f);
        radii[i] = r; my_r = r;
        float xc = fminf(fmaxf(px / VOLF, 0.0f), 1.0f);
        my_iw = expf(-3.0f * xc);
        my_ow = expf(3.0f * (xc - 1.0f));
        e_iw[i] = my_iw; e_ow[i] = my_ow;
        float s = 0.0f;
        #pragma unroll
        for (int k = 0; k < FD; k++) { float v = features[(size_t)i*FD + k]; s += v*v; }
        float nrm = fmaxf(sqrtf(s), 1e-6f);
        #pragma unroll
        for (int k = 0; k < FD; k++) fn[(size_t)i*FD + k] = features[(size_t)i*FD + k] / nrm;
    }
    red[threadIdx.x] = my_iw; __syncthreads();
    for (int s = 128; s > 0; s >>= 1) { if (threadIdx.x < s) red[threadIdx.x] += red[threadIdx.x + s]; __syncthreads(); }
    if (threadIdx.x == 0) atomicAdd(&scal[0], red[0]);
    __syncthreads();
    red[threadIdx.x] = my_ow; __syncthreads();
    for (int s = 128; s > 0; s >>= 1) { if (threadIdx.x < s) red[threadIdx.x] += red[threadIdx.x + s]; __syncthreads(); }
    if (threadIdx.x == 0) atomicAdd(&scal[1], red[0]);
    if (i < N) atomicMax((int*)&scal[2], __float_as_int(my_r));
}

// ---------------- K2: deterministic counting-sort binning (1 wave per cell) ----------------
__global__ __launch_bounds__(64) void k_binfill(
    const float* __restrict__ posx4, float4* __restrict__ posb, int* __restrict__ jmap,
    int* __restrict__ binoff, int* __restrict__ bincnt, int N)
{
    int c = blockIdx.x, lane = threadIdx.x;
    int offs = 0, mine = 0;
    for (int jb = 0; jb < N; jb += 64) {               // N multiple of 64
        float4 q = ((const float4*)posx4)[jb + lane];
        int ix = min(NCD-1, (int)(q.x * (1.0f/CELLW)));
        int iy = min(NCD-1, (int)(q.y * (1.0f/CELLW)));
        int cj = ix * NCD + iy;
        offs += (int)__popcll(__ballot(cj < c));
        mine += (int)__popcll(__ballot(cj == c));
    }
    unsigned long long lmask = (1ull << lane) - 1ull;
    int w = 0;
    for (int jb = 0; jb < N; jb += 64) {
        int j = jb + lane;
        float4 q = ((const float4*)posx4)[j];
        int ix = min(NCD-1, (int)(q.x * (1.0f/CELLW)));
        int iy = min(NCD-1, (int)(q.y * (1.0f/CELLW)));
        bool hit = (ix * NCD + iy == c);
        unsigned long long m = __ballot(hit);
        if (hit) {
            int pos = offs + w + (int)__popcll(m & lmask);
            posb[pos] = q;
            jmap[pos] = j;
        }
        w += (int)__popcll(m);
    }
    if (lane == 0) { binoff[c] = offs; bincnt[c] = mine; }
}

// ---------------- K3: outer-product partial GEMM: partial[slot][N][64] ----------------
__global__ __launch_bounds__(256) void k_act0(
    const float* __restrict__ xT, const float* __restrict__ Wi,
    float* __restrict__ partial, int N, int IN)
{
    __shared__ float smem[2 * 64 * 68];
    float* wtT = smem;
    int t = threadIdx.x;
    int wave = t >> 6, lane = t & 63;
    int nr = lane >> 2, br = lane & 3;
    int i0 = blockIdx.x * 64;
    int kbase = blockIdx.y * 196;
    float acc[4][16];
    #pragma unroll
    for (int a = 0; a < 4; a++)
        #pragma unroll
        for (int b = 0; b < 16; b++) acc[a][b] = 0.0f;

    for (int c = 0; c < NCHUNK; c++) {
        int k0 = kbase + c * CHUNK;
        __syncthreads();
        for (int fi = t; fi < 64 * (CHUNK/4); fi += 256) {
            int n = fi / (CHUNK/4), q = fi % (CHUNK/4);
            float4 w4 = *(const float4*)(Wi + (size_t)(i0 + n) * IN + k0 + q * 4);
            wtT[(q*4+0)*LDP + n] = w4.x;
            wtT[(q*4+1)*LDP + n] = w4.y;
            wtT[(q*4+2)*LDP + n] = w4.z;
            wtT[(q*4+3)*LDP + n] = w4.w;
        }
        __syncthreads();
        for (int q = ((wave + c) & 3); q < CHUNK/4; q += 4) {
            #pragma unroll
            for (int j = 0; j < 4; j++) {
                int kl = q*4 + j;
                float4 a4 = *(const float4*)(&wtT[kl * LDP + nr*4]);
                const float* xr = xT + (size_t)(k0 + kl) * 64 + br*16;
                float4 b0 = *(const float4*)(xr + 0);
                float4 b1 = *(const float4*)(xr + 4);
                float4 b2 = *(const float4*)(xr + 8);
                float4 b3 = *(const float4*)(xr + 12);
                #pragma unroll
                for (int a = 0; a < 4; a++) {
                    float av = (a==0) ? a4.x : (a==1) ? a4.y : (a==2) ? a4.z : a4.w;
                    acc[a][ 0] += av*b0.x; acc[a][ 1] += av*b0.y; acc[a][ 2] += av*b0.z; acc[a][ 3] += av*b0.w;
                    acc[a][ 4] += av*b1.x; acc[a][ 5] += av*b1.y; acc[a][ 6] += av*b1.z; acc[a][ 7] += av*b1.w;
                    acc[a][ 8] += av*b2.x; acc[a][ 9] += av*b2.y; acc[a][10] += av*b2.z; acc[a][11] += av*b2.w;
                    acc[a][12] += av*b3.x; acc[a][13] += av*b3.y; acc[a][14] += av*b3.z; acc[a][15] += av*b3.w;
                }
            }
        }
    }
    __syncthreads();
    float4* sm4 = (float4*)smem;
    int g = wave >> 1;
    if (wave & 1) {
        #pragma unroll
        for (int a = 0; a < 4; a++)
            #pragma unroll
            for (int b4 = 0; b4 < 4; b4++)
                sm4[(g*16 + a*4 + b4) * 64 + lane] =
                    make_float4(acc[a][b4*4+0], acc[a][b4*4+1], acc[a][b4*4+2], acc[a][b4*4+3]);
    }
    __syncthreads();
    if (!(wave & 1)) {
        int slot = blockIdx.y * 2 + g;
        size_t pbase = ((size_t)slot * N + i0 + nr*4) * 64 + br*16;
        #pragma unroll
        for (int a = 0; a < 4; a++)
            #pragma unroll
            for (int b4 = 0; b4 < 4; b4++) {
                float4 o = sm4[(g*16 + a*4 + b4) * 64 + lane];
                o.x += acc[a][b4*4+0]; o.y += acc[a][b4*4+1];
                o.z += acc[a][b4*4+2]; o.w += acc[a][b4*4+3];
                *(float4*)(partial + pbase + (size_t)a * 64 + b4*4) = o;
            }
    }
}

// ---------------- K3b: reduce partials, apply input gating ----------------
__global__ __launch_bounds__(256) void k_act0_red(
    const float* __restrict__ partial, const float* __restrict__ e_iw,
    const float* __restrict__ scal, float* __restrict__ actA, int N)
{
    int idx = blockIdx.x * 256 + threadIdx.x;
    int i = idx >> 6;
    size_t stride = (size_t)N * 64;
    float s = 0.0f;
    #pragma unroll
    for (int p = 0; p < PS; p++) s += partial[p * stride + idx];
    float inv = 1.0f / (scal[0] + 1e-6f);
    actA[idx] = s * (e_iw[i] * inv);
}

// ---------------- K4 helper ----------------
// EXACT reference predicate: dist = sqrtf(max(d2,0)); hit = dist < maxr.
__device__ __forceinline__ void scan_body(
    const float4& p, const float4& q, int j, float maxr, bool act,
    unsigned long long lmask, int2* __restrict__ ep, size_t base, int& cnt)
{
    float d2 = fmaxf(p.w + q.w - 2.0f*(p.x*q.x + p.y*q.y + p.z*q.z), 0.0f);
    float dist = sqrtf(d2);
    bool hit = act && (dist < maxr);
    unsigned long long m = __ballot(hit);
    if (m) {
        if (hit) {
            int pos = cnt + (int)__popcll(m & lmask);
            if (pos < MAXN) ep[base + pos] = make_int2(j, __float_as_int(dist));
        }
        cnt += (int)__popcll(m);
    }
}

// ---------------- K4: binned scan — wave owns 2 binned-consecutive rows ----------------
__global__ __launch_bounds__(256) void k_scan(
    const float4* __restrict__ posb, const int* __restrict__ jmap,
    const float* __restrict__ scal, int2* __restrict__ ep, int* __restrict__ nbr_cnt,
    const int* __restrict__ binoff, const int* __restrict__ bincnt, int N)
{
    int wave = threadIdx.x >> 6, lane = threadIdx.x & 63;
    int s0 = (blockIdx.x * 4 + wave) * 2;
    float4 p0 = posb[s0], p1 = posb[s0 + 1];
    int r0 = jmap[s0], r1 = jmap[s0 + 1];
    float maxr = __int_as_float(((const int*)scal)[2]);
    int R = (int)ceilf(maxr * (1.0f/CELLW));
    int cxa = min(NCD-1, (int)(p0.x * (1.0f/CELLW))), cya = min(NCD-1, (int)(p0.y * (1.0f/CELLW)));
    int cxb = min(NCD-1, (int)(p1.x * (1.0f/CELLW))), cyb = min(NCD-1, (int)(p1.y * (1.0f/CELLW)));
    int ix0 = max(0, min(cxa, cxb) - R), ix1 = min(NCD-1, max(cxa, cxb) + R);
    int iy0 = max(0, min(cya, cyb) - R), iy1 = min(NCD-1, max(cya, cyb) + R);
    unsigned long long lmask = (1ull << lane) - 1ull;
    int c0 = 0, c1 = 0;
    size_t base0 = (size_t)r0 * MAXN, base1 = (size_t)r1 * MAXN;
    for (int ix = ix0; ix <= ix1; ix++)
    for (int iy = iy0; iy <= iy1; iy++) {
        int c = ix * NCD + iy;
        int bs = binoff[c], cnt = bincnt[c];
        for (int sb = 0; sb < cnt; sb += 64) {
            bool act = (sb + lane) < cnt;
            int s = act ? (bs + sb + lane) : bs;
            float4 q = posb[s];
            int j = jmap[s];
            scan_body(p0, q, j, maxr, act, lmask, ep, base0, c0);
            scan_body(p1, q, j, maxr, act, lmask, ep, base1, c1);
        }
    }
    if (lane == 0) {
        nbr_cnt[r0] = min(c0, MAXN);
        nbr_cnt[r1] = min(c1, MAXN);
    }
}

// ---------------- K5: weight computation, 8 lanes per edge (separate, wide grid) ----------------
__global__ __launch_bounds__(256) void k_weight(
    const float* __restrict__ fn, const float* __restrict__ radii,
    int2* __restrict__ ep /* in: (j,dist), out: (j,w) */,
    const int* __restrict__ nbr_cnt, float* __restrict__ rowinv, int N)
{
    int i = blockIdx.x;
    int lane = threadIdx.x & 63;
    int wave = threadIdx.x >> 6;
    int sub = lane & 7;
    int eg  = lane >> 3;
    float4 fni = ((const float4*)(fn + (size_t)i * FD))[sub];
    float inv_ri = 1.0f / (radii[i] + 1e-6f);
    int cnt = nbr_cnt[i];
    float s = 0.0f;
    for (int e0 = wave * 8; e0 < cnt; e0 += 32) {
        int e = e0 + eg;
        bool act = e < cnt;
        int ecl = act ? e : (cnt - 1);
        int2 edge = ep[(size_t)i * MAXN + ecl];
        int j      = edge.x;
        float dist = __int_as_float(edge.y);
        float4 fj = ((const float4*)(fn + (size_t)j * FD))[sub];
        float fs = fni.x*fj.x + fni.y*fj.y + fni.z*fj.z + fni.w*fj.w;
        fs += __shfl_xor(fs, 1, 64);
        fs += __shfl_xor(fs, 2, 64);
        fs += __shfl_xor(fs, 4, 64);
        fs = fminf(fmaxf(fs, -1.0f), 1.0f);
        float w = expf(-fminf(dist * inv_ri, 20.0f)) * (0.3f + 0.7f * fs);
        if (act && sub == 0) {
            ((float*)&ep[(size_t)i * MAXN + e])[1] = w;
            s += w;
        }
    }
    __shared__ float red[256];
    red[threadIdx.x] = s; __syncthreads();
    for (int st = 128; st > 0; st >>= 1) { if (threadIdx.x < st) red[threadIdx.x] += red[threadIdx.x + st]; __syncthreads(); }
    if (threadIdx.x == 0) rowinv[i] = 1.0f / (red[0] + 1e-6f);
}

// ---------------- K6: one iteration (sparse matvec over 64 batches) ----------------
__global__ __launch_bounds__(256) void k_iter(
    const float* __restrict__ actIn, float* __restrict__ actOut,
    const int2* __restrict__ ep, const int* __restrict__ nbr_cnt,
    const float* __restrict__ rowinv, const float* __restrict__ thr,
    const int* __restrict__ nIterPtr, int iterIdx, int N)
{
    if (iterIdx >= min(*nIterPtr, MAX_LAUNCH_ITERS)) return;
    int i = blockIdx.x;
    int wave = threadIdx.x >> 6, lane = threadIdx.x & 63;
    int cnt = nbr_cnt[i];
    float acc = 0.0f;
    for (int e = wave; e < cnt; e += 4) {
        int2 edge = ep[(size_t)i * MAXN + e];
        acc += actIn[(size_t)edge.x * 64 + lane] * __int_as_float(edge.y);
    }
    __shared__ float redA[4 * 64];
    redA[wave * 64 + lane] = acc;
    __syncthreads();
    if (wave == 0) {
        float tot = redA[lane] + redA[64 + lane] + redA[128 + lane] + redA[192 + lane];
        float v = actIn[(size_t)i * 64 + lane] + tot * rowinv[i] - thr[i];
        v = fminf(fmaxf(v, 0.0f), 100.0f);
        actOut[(size_t)i * 64 + lane] = v;
    }
}

// ---------------- K7a: output projection partials ----------------
__global__ __launch_bounds__(256) void k_out1(
    const float* __restrict__ actA, const float* __restrict__ actB,
    const int* __restrict__ nIterPtr, const float* __restrict__ e_ow,
    const float* __restrict__ scal, const float* __restrict__ outW,
    float* __restrict__ outPart, int N)
{
    int m = min(*nIterPtr, MAX_LAUNCH_ITERS);
    const float* actF = (m & 1) ? actB : actA;
    int wave = threadIdx.x >> 6, lane = threadIdx.x & 63;
    float inv = 1.0f / (scal[1] + 1e-6f);
    float acc[OUT_DIM];
    #pragma unroll
    for (int o = 0; o < OUT_DIM; o++) acc[o] = 0.0f;
    for (int i = blockIdx.x * 4 + wave; i < N; i += OB * 4) {
        float a = actF[(size_t)i * 64 + lane] * (e_ow[i] * inv);
        const float* wo = outW + (size_t)i * OUT_DIM;
        #pragma unroll
        for (int o = 0; o < OUT_DIM; o++) acc[o] += a * wo[o];
    }
    __shared__ float red[4][OUT_DIM][64];
    #pragma unroll
    for (int o = 0; o < OUT_DIM; o++) red[wave][o][lane] = acc[o];
    __syncthreads();
    if (wave == 0) {
        #pragma unroll
        for (int o = 0; o < OUT_DIM; o++) {
            float s = red[0][o][lane] + red[1][o][lane] + red[2][o][lane] + red[3][o][lane];
            outPart[((size_t)blockIdx.x * OUT_DIM + o) * 64 + lane] = s;
        }
    }
}

// ---------------- K7b: reduce partials -> out ----------------
__global__ __launch_bounds__(256) void k_out2(
    const float* __restrict__ outPart, float* __restrict__ out)
{
    int t = blockIdx.x * 256 + threadIdx.x;
    if (t >= 64 * OUT_DIM) return;
    int b = t / OUT_DIM, o = t % OUT_DIM;
    float s = 0.0f;
    for (int blk = 0; blk < OB; blk++)
        s += outPart[((size_t)blk * OUT_DIM + o) * 64 + b];
    out[t] = s;
}

extern "C" void kernel_launch(void* const* d_in, const int* in_sizes, int n_in,
                              void* d_out, int out_size, void* d_ws, size_t ws_size,
                              hipStream_t stream)
{
    const float* x        = (const float*)d_in[0];
    const float* positions= (const float*)d_in[1];
    const float* Win      = (const float*)d_in[2];
    const float* features = (const float*)d_in[3];
    const float* Wout     = (const float*)d_in[4];
    const float* radii_in = (const float*)d_in[5];
    const float* thr      = (const float*)d_in[6];
    const int*   nIter    = (const int*)  d_in[7];

    const int N  = in_sizes[5];            // 8000
    const int IN = in_sizes[2] / N;        // 784
    const int B  = in_sizes[0] / IN;       // 64 (kernels assume 64 = wave size)
    (void)B;

    float* ws = (float*)d_ws;
    size_t off = 0;
    auto alloc = [&](size_t nfloats) { size_t cur = off; off += (nfloats + 63) & ~(size_t)63; return cur; };
    float* xT      = ws + alloc((size_t)B * IN);
    float* posx4   = ws + alloc((size_t)N * 4);
    float* radii   = ws + alloc(N);
    float* e_iw    = ws + alloc(N);
    float* e_ow    = ws + alloc(N);
    float* rowinv  = ws + alloc(N);
    float* scal    = ws + alloc(4);
    float* outPart = ws + alloc((size_t)OB * OUT_DIM * 64);
    float* fn      = ws + alloc((size_t)N * FD);
    float* actA    = ws + alloc((size_t)N * 64);
    float* actB    = ws + alloc((size_t)N * 64);
    float4* posb   = (float4*)(ws + alloc((size_t)N * 4));
    int*   jmap    = (int*)(ws + alloc(N));
    int*   binoff  = (int*)(ws + alloc(64));
    int*   bincnt  = (int*)(ws + alloc(64));
    int2*  ep      = (int2*)(ws + alloc((size_t)N * MAXN * 2));   // packed (j, dist/w)
    int*   nbr_cnt = (int*)(ws + alloc(N));
    // partial[PS][N][64] aliased onto ep (consumed by k_act0_red before k_scan writes ep)
    float* partial = (float*)ep;   // PS*N*64 = 4.096M floats <= N*MAXN*2 = 5.12M floats

    hipMemsetAsync(scal, 0, 4 * sizeof(float), stream);

    int nxt = (IN + 63) / 64;              // 13 transpose blocks
    int npre = (N + 255) / 256;            // 32 preprocess blocks
    k_prext<<<nxt + npre, 256, 0, stream>>>(x, positions, radii_in, features,
                                            xT, posx4, radii, e_iw, e_ow, fn, scal,
                                            N, IN, nxt);
    k_binfill<<<NCELL, 64, 0, stream>>>(posx4, posb, jmap, binoff, bincnt, N);
    k_act0<<<dim3(N / 64, 4), 256, 0, stream>>>(xT, Win, partial, N, IN);
    k_act0_red<<<(N * 64) / 256, 256, 0, stream>>>(partial, e_iw, scal, actA, N);
    k_scan<<<N / 8, 256, 0, stream>>>(posb, jmap, scal, ep, nbr_cnt, binoff, bincnt, N);
    k_weight<<<N, 256, 0, stream>>>(fn, radii, ep, nbr_cnt, rowinv, N);

    float* bufs[2] = {actA, actB};
    for (int it = 0; it < MAX_LAUNCH_ITERS; it++) {
        k_iter<<<N, 256, 0, stream>>>(bufs[it & 1], bufs[(it + 1) & 1],
                                      ep, nbr_cnt, rowinv, thr, nIter, it, N);
    }
    k_out1<<<OB, 256, 0, stream>>>(actA, actB, nIter, e_ow, scal, Wout, outPart, N);
    k_out2<<<3, 256, 0, stream>>>(outPart, (float*)d_out);
}

// Round 12
// 259.840 us; speedup vs baseline: 1.1970x; 1.1970x over previous
//
#include <hip/hip_runtime.h>
#include <hip/hip_bf16.h>
#include <math.h>

#define VOLF 100.0f
#define FD 32
#define OUT_DIM 10
#define MAXN 320
#define MAX_LAUNCH_ITERS 4
#define OB 128     // k_out partial blocks
#define CHUNK 28   // k_act0: k's per LDS chunk
#define NCHUNK 7   // 196/28 chunks per block
#define LDP 68     // padded wtT row stride
#define PS 8       // partial slots
#define NCD 5      // bin cells per dim (x,y)
#define CELLW 20.0f
#define NCELL (NCD*NCD)
#define NG 125     // 64-point chunks (N/64)
#define GP 128     // padded chunk stride

// ---------------- K1: merged tiled x-transpose + preprocess + cell histogram ----------------
__global__ __launch_bounds__(256) void k_prext(
    const float* __restrict__ x, const float* __restrict__ positions,
    const float* __restrict__ radii_in, const float* __restrict__ features,
    float* __restrict__ xT, float* __restrict__ posx4,
    float* __restrict__ radii, float* __restrict__ e_iw, float* __restrict__ e_ow,
    float* __restrict__ fn, float* __restrict__ scal, int* __restrict__ hist,
    int N, int IN, int nxt)
{
    __shared__ float tile[64][65];
    __shared__ float red[256];
    if ((int)blockIdx.x < nxt) {           // tiled transpose: 64 k x 64 b per block
        int w = threadIdx.x >> 6, lane = threadIdx.x & 63;
        int k0 = blockIdx.x * 64;
        #pragma unroll
        for (int r = 0; r < 16; r++) {
            int b = w * 16 + r;
            int k = k0 + lane;
            if (k < IN) tile[lane][b] = x[(size_t)b * IN + k];
        }
        __syncthreads();
        #pragma unroll
        for (int r = 0; r < 16; r++) {
            int kl = w * 16 + r;
            int k = k0 + kl;
            if (k < IN) xT[(size_t)k * 64 + lane] = tile[kl][lane];
        }
        return;
    }
    int i = (blockIdx.x - nxt) * 256 + threadIdx.x;
    int lane = threadIdx.x & 63;
    float my_iw = 0.0f, my_ow = 0.0f, my_r = 0.0f;
    int ci = 31;                           // invalid cell
    if (i < N) {
        float px = fminf(fmaxf(positions[3*i+0], 0.1f), VOLF - 0.1f);
        float py = fminf(fmaxf(positions[3*i+1], 0.1f), VOLF - 0.1f);
        float pz = fminf(fmaxf(positions[3*i+2], 0.1f), VOLF - 0.1f);
        float sq = px*px + py*py + pz*pz;
        posx4[4*i+0] = px; posx4[4*i+1] = py; posx4[4*i+2] = pz; posx4[4*i+3] = sq;
        int ix = min(NCD-1, (int)(px * (1.0f/CELLW)));
        int iy = min(NCD-1, (int)(py * (1.0f/CELLW)));
        ci = ix * NCD + iy;
        float r = fminf(fmaxf(radii_in[i], 1.0f), 50.0f);
        radii[i] = r; my_r = r;
        float xc = fminf(fmaxf(px / VOLF, 0.0f), 1.0f);
        my_iw = expf(-3.0f * xc);
        my_ow = expf(3.0f * (xc - 1.0f));
        e_iw[i] = my_iw; e_ow[i] = my_ow;
        float s = 0.0f;
        #pragma unroll
        for (int k = 0; k < FD; k++) { float v = features[(size_t)i*FD + k]; s += v*v; }
        float nrm = fmaxf(sqrtf(s), 1e-6f);
        #pragma unroll
        for (int k = 0; k < FD; k++) fn[(size_t)i*FD + k] = features[(size_t)i*FD + k] / nrm;
    }
    // per-64-chunk cell histogram (wave-uniform chunk g)
    int g = i >> 6;
    if (g < NG) {
        int cnt = 0;
        #pragma unroll
        for (int c = 0; c < NCELL; c++) {
            unsigned long long m = __ballot(ci == c);
            if (lane == c) cnt = (int)__popcll(m);
        }
        if (lane < NCELL) hist[lane * GP + g] = cnt;
    }
    red[threadIdx.x] = my_iw; __syncthreads();
    for (int s = 128; s > 0; s >>= 1) { if (threadIdx.x < s) red[threadIdx.x] += red[threadIdx.x + s]; __syncthreads(); }
    if (threadIdx.x == 0) atomicAdd(&scal[0], red[0]);
    __syncthreads();
    red[threadIdx.x] = my_ow; __syncthreads();
    for (int s = 128; s > 0; s >>= 1) { if (threadIdx.x < s) red[threadIdx.x] += red[threadIdx.x + s]; __syncthreads(); }
    if (threadIdx.x == 0) atomicAdd(&scal[1], red[0]);
    if (i < N) atomicMax((int*)&scal[2], __float_as_int(my_r));
}

// ---------------- K2a: prefix over cells + per-chunk starts (1 wave) ----------------
__global__ __launch_bounds__(64) void k_prefix(
    const int* __restrict__ hist, int* __restrict__ start,
    int* __restrict__ binoff, int* __restrict__ bincnt)
{
    __shared__ int tot[NCELL], boff[NCELL];
    int lane = threadIdx.x;
    if (lane < NCELL) {
        int s = 0;
        for (int g = 0; g < NG; g++) s += hist[lane * GP + g];
        tot[lane] = s;
    }
    __syncthreads();
    if (lane == 0) {
        int s = 0;
        for (int c = 0; c < NCELL; c++) { boff[c] = s; s += tot[c]; }
    }
    __syncthreads();
    if (lane < NCELL) {
        int s = boff[lane];
        binoff[lane] = s;
        bincnt[lane] = tot[lane];
        for (int g = 0; g < NG; g++) {
            start[lane * GP + g] = s;
            s += hist[lane * GP + g];
        }
    }
}

// ---------------- K2b: deterministic scatter (wave = 64-pt chunk) ----------------
__global__ __launch_bounds__(64) void k_scatter(
    const float* __restrict__ posx4, const int* __restrict__ start,
    float4* __restrict__ posb, int* __restrict__ jmap, int N)
{
    int g = blockIdx.x, lane = threadIdx.x;
    int j = g * 64 + lane;
    float4 q = ((const float4*)posx4)[j];
    int ix = min(NCD-1, (int)(q.x * (1.0f/CELLW)));
    int iy = min(NCD-1, (int)(q.y * (1.0f/CELLW)));
    int ci = ix * NCD + iy;
    unsigned long long lmask = (1ull << lane) - 1ull;
    int rank = 0;
    #pragma unroll
    for (int c = 0; c < NCELL; c++) {
        unsigned long long m = __ballot(ci == c);
        if (ci == c) rank = (int)__popcll(m & lmask);
    }
    int pos = start[ci * GP + g] + rank;
    posb[pos] = q;
    jmap[pos] = j;
}

// ---------------- K3: outer-product partial GEMM: partial[slot][N][64] ----------------
__global__ __launch_bounds__(256) void k_act0(
    const float* __restrict__ xT, const float* __restrict__ Wi,
    float* __restrict__ partial, int N, int IN)
{
    __shared__ float smem[2 * 64 * 68];
    float* wtT = smem;
    int t = threadIdx.x;
    int wave = t >> 6, lane = t & 63;
    int nr = lane >> 2, br = lane & 3;
    int i0 = blockIdx.x * 64;
    int kbase = blockIdx.y * 196;
    float acc[4][16];
    #pragma unroll
    for (int a = 0; a < 4; a++)
        #pragma unroll
        for (int b = 0; b < 16; b++) acc[a][b] = 0.0f;

    for (int c = 0; c < NCHUNK; c++) {
        int k0 = kbase + c * CHUNK;
        __syncthreads();
        for (int fi = t; fi < 64 * (CHUNK/4); fi += 256) {
            int n = fi / (CHUNK/4), q = fi % (CHUNK/4);
            float4 w4 = *(const float4*)(Wi + (size_t)(i0 + n) * IN + k0 + q * 4);
            wtT[(q*4+0)*LDP + n] = w4.x;
            wtT[(q*4+1)*LDP + n] = w4.y;
            wtT[(q*4+2)*LDP + n] = w4.z;
            wtT[(q*4+3)*LDP + n] = w4.w;
        }
        __syncthreads();
        for (int q = ((wave + c) & 3); q < CHUNK/4; q += 4) {
            #pragma unroll
            for (int j = 0; j < 4; j++) {
                int kl = q*4 + j;
                float4 a4 = *(const float4*)(&wtT[kl * LDP + nr*4]);
                const float* xr = xT + (size_t)(k0 + kl) * 64 + br*16;
                float4 b0 = *(const float4*)(xr + 0);
                float4 b1 = *(const float4*)(xr + 4);
                float4 b2 = *(const float4*)(xr + 8);
                float4 b3 = *(const float4*)(xr + 12);
                #pragma unroll
                for (int a = 0; a < 4; a++) {
                    float av = (a==0) ? a4.x : (a==1) ? a4.y : (a==2) ? a4.z : a4.w;
                    acc[a][ 0] += av*b0.x; acc[a][ 1] += av*b0.y; acc[a][ 2] += av*b0.z; acc[a][ 3] += av*b0.w;
                    acc[a][ 4] += av*b1.x; acc[a][ 5] += av*b1.y; acc[a][ 6] += av*b1.z; acc[a][ 7] += av*b1.w;
                    acc[a][ 8] += av*b2.x; acc[a][ 9] += av*b2.y; acc[a][10] += av*b2.z; acc[a][11] += av*b2.w;
                    acc[a][12] += av*b3.x; acc[a][13] += av*b3.y; acc[a][14] += av*b3.z; acc[a][15] += av*b3.w;
                }
            }
        }
    }
    __syncthreads();
    float4* sm4 = (float4*)smem;
    int g = wave >> 1;
    if (wave & 1) {
        #pragma unroll
        for (int a = 0; a < 4; a++)
            #pragma unroll
            for (int b4 = 0; b4 < 4; b4++)
                sm4[(g*16 + a*4 + b4) * 64 + lane] =
                    make_float4(acc[a][b4*4+0], acc[a][b4*4+1], acc[a][b4*4+2], acc[a][b4*4+3]);
    }
    __syncthreads();
    if (!(wave & 1)) {
        int slot = blockIdx.y * 2 + g;
        size_t pbase = ((size_t)slot * N + i0 + nr*4) * 64 + br*16;
        #pragma unroll
        for (int a = 0; a < 4; a++)
            #pragma unroll
            for (int b4 = 0; b4 < 4; b4++) {
                float4 o = sm4[(g*16 + a*4 + b4) * 64 + lane];
                o.x += acc[a][b4*4+0]; o.y += acc[a][b4*4+1];
                o.z += acc[a][b4*4+2]; o.w += acc[a][b4*4+3];
                *(float4*)(partial + pbase + (size_t)a * 64 + b4*4) = o;
            }
    }
}

// ---------------- K3b: reduce partials, apply input gating ----------------
__global__ __launch_bounds__(256) void k_act0_red(
    const float* __restrict__ partial, const float* __restrict__ e_iw,
    const float* __restrict__ scal, float* __restrict__ actA, int N)
{
    int idx = blockIdx.x * 256 + threadIdx.x;
    int i = idx >> 6;
    size_t stride = (size_t)N * 64;
    float s = 0.0f;
    #pragma unroll
    for (int p = 0; p < PS; p++) s += partial[p * stride + idx];
    float inv = 1.0f / (scal[0] + 1e-6f);
    actA[idx] = s * (e_iw[i] * inv);
}

// ---------------- K4 helper ----------------
// EXACT reference predicate: dist = sqrtf(max(d2,0)); hit = dist < maxr.
__device__ __forceinline__ void scan_body(
    const float4& p, const float4& q, int j, float maxr, bool act,
    unsigned long long lmask, int2* __restrict__ ep, size_t base, int& cnt)
{
    float d2 = fmaxf(p.w + q.w - 2.0f*(p.x*q.x + p.y*q.y + p.z*q.z), 0.0f);
    float dist = sqrtf(d2);
    bool hit = act && (dist < maxr);
    unsigned long long m = __ballot(hit);
    if (m) {
        if (hit) {
            int pos = cnt + (int)__popcll(m & lmask);
            if (pos < MAXN) ep[base + pos] = make_int2(j, __float_as_int(dist));
        }
        cnt += (int)__popcll(m);
    }
}

// ---------------- K4: binned scan — wave owns 2 binned-consecutive rows ----------------
__global__ __launch_bounds__(256) void k_scan(
    const float4* __restrict__ posb, const int* __restrict__ jmap,
    const float* __restrict__ scal, int2* __restrict__ ep, int* __restrict__ nbr_cnt,
    const int* __restrict__ binoff, const int* __restrict__ bincnt, int N)
{
    int wave = threadIdx.x >> 6, lane = threadIdx.x & 63;
    int s0 = (blockIdx.x * 4 + wave) * 2;
    float4 p0 = posb[s0], p1 = posb[s0 + 1];
    int r0 = jmap[s0], r1 = jmap[s0 + 1];
    float maxr = __int_as_float(((const int*)scal)[2]);
    int R = (int)ceilf(maxr * (1.0f/CELLW));
    int cxa = min(NCD-1, (int)(p0.x * (1.0f/CELLW))), cya = min(NCD-1, (int)(p0.y * (1.0f/CELLW)));
    int cxb = min(NCD-1, (int)(p1.x * (1.0f/CELLW))), cyb = min(NCD-1, (int)(p1.y * (1.0f/CELLW)));
    int ix0 = max(0, min(cxa, cxb) - R), ix1 = min(NCD-1, max(cxa, cxb) + R);
    int iy0 = max(0, min(cya, cyb) - R), iy1 = min(NCD-1, max(cya, cyb) + R);
    unsigned long long lmask = (1ull << lane) - 1ull;
    int c0 = 0, c1 = 0;
    size_t base0 = (size_t)r0 * MAXN, base1 = (size_t)r1 * MAXN;
    for (int ix = ix0; ix <= ix1; ix++)
    for (int iy = iy0; iy <= iy1; iy++) {
        int c = ix * NCD + iy;
        int bs = binoff[c], cnt = bincnt[c];
        for (int sb = 0; sb < cnt; sb += 64) {
            bool act = (sb + lane) < cnt;
            int s = act ? (bs + sb + lane) : bs;
            float4 q = posb[s];
            int j = jmap[s];
            scan_body(p0, q, j, maxr, act, lmask, ep, base0, c0);
            scan_body(p1, q, j, maxr, act, lmask, ep, base1, c1);
        }
    }
    if (lane == 0) {
        nbr_cnt[r0] = min(c0, MAXN);
        nbr_cnt[r1] = min(c1, MAXN);
    }
}

// ---------------- K5: weight computation, 8 lanes per edge ----------------
__global__ __launch_bounds__(256) void k_weight(
    const float* __restrict__ fn, const float* __restrict__ radii,
    int2* __restrict__ ep /* in: (j,dist), out: (j,w) */,
    const int* __restrict__ nbr_cnt, float* __restrict__ rowinv, int N)
{
    int i = blockIdx.x;
    int lane = threadIdx.x & 63;
    int wave = threadIdx.x >> 6;
    int sub = lane & 7;
    int eg  = lane >> 3;
    float4 fni = ((const float4*)(fn + (size_t)i * FD))[sub];
    float inv_ri = 1.0f / (radii[i] + 1e-6f);
    int cnt = nbr_cnt[i];
    float s = 0.0f;
    for (int e0 = wave * 8; e0 < cnt; e0 += 32) {
        int e = e0 + eg;
        bool act = e < cnt;
        int ecl = act ? e : (cnt - 1);
        int2 edge = ep[(size_t)i * MAXN + ecl];
        int j      = edge.x;
        float dist = __int_as_float(edge.y);
        float4 fj = ((const float4*)(fn + (size_t)j * FD))[sub];
        float fs = fni.x*fj.x + fni.y*fj.y + fni.z*fj.z + fni.w*fj.w;
        fs += __shfl_xor(fs, 1, 64);
        fs += __shfl_xor(fs, 2, 64);
        fs += __shfl_xor(fs, 4, 64);
        fs = fminf(fmaxf(fs, -1.0f), 1.0f);
        float w = expf(-fminf(dist * inv_ri, 20.0f)) * (0.3f + 0.7f * fs);
        if (act && sub == 0) {
            ((float*)&ep[(size_t)i * MAXN + e])[1] = w;
            s += w;
        }
    }
    __shared__ float red[256];
    red[threadIdx.x] = s; __syncthreads();
    for (int st = 128; st > 0; st >>= 1) { if (threadIdx.x < st) red[threadIdx.x] += red[threadIdx.x + st]; __syncthreads(); }
    if (threadIdx.x == 0) rowinv[i] = 1.0f / (red[0] + 1e-6f);
}

// ---------------- K6: one iteration (sparse matvec over 64 batches) ----------------
__global__ __launch_bounds__(256) void k_iter(
    const float* __restrict__ actIn, float* __restrict__ actOut,
    const int2* __restrict__ ep, const int* __restrict__ nbr_cnt,
    const float* __restrict__ rowinv, const float* __restrict__ thr,
    const int* __restrict__ nIterPtr, int iterIdx, int N)
{
    if (iterIdx >= min(*nIterPtr, MAX_LAUNCH_ITERS)) return;
    int i = blockIdx.x;
    int wave = threadIdx.x >> 6, lane = threadIdx.x & 63;
    int cnt = nbr_cnt[i];
    float acc = 0.0f;
    for (int e = wave; e < cnt; e += 4) {
        int2 edge = ep[(size_t)i * MAXN + e];
        acc += actIn[(size_t)edge.x * 64 + lane] * __int_as_float(edge.y);
    }
    __shared__ float redA[4 * 64];
    redA[wave * 64 + lane] = acc;
    __syncthreads();
    if (wave == 0) {
        float tot = redA[lane] + redA[64 + lane] + redA[128 + lane] + redA[192 + lane];
        float v = actIn[(size_t)i * 64 + lane] + tot * rowinv[i] - thr[i];
        v = fminf(fmaxf(v, 0.0f), 100.0f);
        actOut[(size_t)i * 64 + lane] = v;
    }
}

// ---------------- K7a: output projection partials ----------------
__global__ __launch_bounds__(256) void k_out1(
    const float* __restrict__ actA, const float* __restrict__ actB,
    const int* __restrict__ nIterPtr, const float* __restrict__ e_ow,
    const float* __restrict__ scal, const float* __restrict__ outW,
    float* __restrict__ outPart, int N)
{
    int m = min(*nIterPtr, MAX_LAUNCH_ITERS);
    const float* actF = (m & 1) ? actB : actA;
    int wave = threadIdx.x >> 6, lane = threadIdx.x & 63;
    float inv = 1.0f / (scal[1] + 1e-6f);
    float acc[OUT_DIM];
    #pragma unroll
    for (int o = 0; o < OUT_DIM; o++) acc[o] = 0.0f;
    for (int i = blockIdx.x * 4 + wave; i < N; i += OB * 4) {
        float a = actF[(size_t)i * 64 + lane] * (e_ow[i] * inv);
        const float* wo = outW + (size_t)i * OUT_DIM;
        #pragma unroll
        for (int o = 0; o < OUT_DIM; o++) acc[o] += a * wo[o];
    }
    __shared__ float red[4][OUT_DIM][64];
    #pragma unroll
    for (int o = 0; o < OUT_DIM; o++) red[wave][o][lane] = acc[o];
    __syncthreads();
    if (wave == 0) {
        #pragma unroll
        for (int o = 0; o < OUT_DIM; o++) {
            float s = red[0][o][lane] + red[1][o][lane] + red[2][o][lane] + red[3][o][lane];
            outPart[((size_t)blockIdx.x * OUT_DIM + o) * 64 + lane] = s;
        }
    }
}

// ---------------- K7b: reduce partials -> out ----------------
__global__ __launch_bounds__(256) void k_out2(
    const float* __restrict__ outPart, float* __restrict__ out)
{
    int t = blockIdx.x * 256 + threadIdx.x;
    if (t >= 64 * OUT_DIM) return;
    int b = t / OUT_DIM, o = t % OUT_DIM;
    float s = 0.0f;
    for (int blk = 0; blk < OB; blk++)
        s += outPart[((size_t)blk * OUT_DIM + o) * 64 + b];
    out[t] = s;
}

extern "C" void kernel_launch(void* const* d_in, const int* in_sizes, int n_in,
                              void* d_out, int out_size, void* d_ws, size_t ws_size,
                              hipStream_t stream)
{
    const float* x        = (const float*)d_in[0];
    const float* positions= (const float*)d_in[1];
    const float* Win      = (const float*)d_in[2];
    const float* features = (const float*)d_in[3];
    const float* Wout     = (const float*)d_in[4];
    const float* radii_in = (const float*)d_in[5];
    const float* thr      = (const float*)d_in[6];
    const int*   nIter    = (const int*)  d_in[7];

    const int N  = in_sizes[5];            // 8000
    const int IN = in_sizes[2] / N;        // 784
    const int B  = in_sizes[0] / IN;       // 64 (kernels assume 64 = wave size)
    (void)B;

    float* ws = (float*)d_ws;
    size_t off = 0;
    auto alloc = [&](size_t nfloats) { size_t cur = off; off += (nfloats + 63) & ~(size_t)63; return cur; };
    float* xT      = ws + alloc((size_t)B * IN);
    float* posx4   = ws + alloc((size_t)N * 4);
    float* radii   = ws + alloc(N);
    float* e_iw    = ws + alloc(N);
    float* e_ow    = ws + alloc(N);
    float* rowinv  = ws + alloc(N);
    float* scal    = ws + alloc(4);
    float* outPart = ws + alloc((size_t)OB * OUT_DIM * 64);
    float* fn      = ws + alloc((size_t)N * FD);
    float* actA    = ws + alloc((size_t)N * 64);
    float* actB    = ws + alloc((size_t)N * 64);
    float4* posb   = (float4*)(ws + alloc((size_t)N * 4));
    int*   jmap    = (int*)(ws + alloc(N));
    int*   hist    = (int*)(ws + alloc(NCELL * GP));
    int*   startA  = (int*)(ws + alloc(NCELL * GP));
    int*   binoff  = (int*)(ws + alloc(64));
    int*   bincnt  = (int*)(ws + alloc(64));
    int2*  ep      = (int2*)(ws + alloc((size_t)N * MAXN * 2));   // packed (j, dist/w)
    int*   nbr_cnt = (int*)(ws + alloc(N));
    // partial[PS][N][64] aliased onto ep (consumed by k_act0_red before k_scan writes ep)
    float* partial = (float*)ep;   // PS*N*64 = 4.096M floats <= N*MAXN*2 = 5.12M floats

    hipMemsetAsync(scal, 0, 4 * sizeof(float), stream);

    int nxt = (IN + 63) / 64;              // 13 transpose blocks
    int npre = (N + 255) / 256;            // 32 preprocess blocks
    k_prext<<<nxt + npre, 256, 0, stream>>>(x, positions, radii_in, features,
                                            xT, posx4, radii, e_iw, e_ow, fn, scal, hist,
                                            N, IN, nxt);
    k_prefix<<<1, 64, 0, stream>>>(hist, startA, binoff, bincnt);
    k_scatter<<<NG, 64, 0, stream>>>(posx4, startA, posb, jmap, N);
    k_act0<<<dim3(N / 64, 4), 256, 0, stream>>>(xT, Win, partial, N, IN);
    k_act0_red<<<(N * 64) / 256, 256, 0, stream>>>(partial, e_iw, scal, actA, N);
    k_scan<<<N / 8, 256, 0, stream>>>(posb, jmap, scal, ep, nbr_cnt, binoff, bincnt, N);
    k_weight<<<N, 256, 0, stream>>>(fn, radii, ep, nbr_cnt, rowinv, N);

    float* bufs[2] = {actA, actB};
    for (int it = 0; it < MAX_LAUNCH_ITERS; it++) {
        k_iter<<<N, 256, 0, stream>>>(bufs[it & 1], bufs[(it + 1) & 1],
                                      ep, nbr_cnt, rowinv, thr, nIter, it, N);
    }
    k_out1<<<OB, 256, 0, stream>>>(actA, actB, nIter, e_ow, scal, Wout, outPart, N);
    k_out2<<<3, 256, 0, stream>>>(outPart, (float*)d_out);
}